// Round 1
// 424.529 us; speedup vs baseline: 1.0234x; 1.0234x over previous
//
#include <hip/hip_runtime.h>

// 23-qubit batched complex state, 2x2 complex gate on qubit 12.
// DIM = 2^23, BATCH = 4. Axis-12 stride (row-major basis index) = 2^10 rows.
// out = stack([re, im]) of shape (2, DIM, BATCH), fp32.
//
// Pure streaming op: 256 MiB read + 256 MiB write, zero reuse.
// Kernel-time floor at fill-demonstrated BW (~6.4 TB/s): ~84 us.
// This version: non-temporal loads/stores (gfx950 `nt` flag) to bypass
// cache allocation on single-use lines, matching fillBuffer's behavior.

#define NQ 23
#define DIMQ (1 << NQ)
#define BATCH 4
#define TBIT 10  // 2^(23-1-12)

typedef float f4 __attribute__((ext_vector_type(4)));

__global__ __launch_bounds__(256) void gate_q12_kernel(
    const float* __restrict__ sre, const float* __restrict__ sim,
    const float* __restrict__ mre, const float* __restrict__ mim,
    float* __restrict__ out)
{
    const unsigned p = blockIdx.x * blockDim.x + threadIdx.x;  // pair idx, < DIMQ/2
    const unsigned low  = p & ((1u << TBIT) - 1u);
    const unsigned high = p >> TBIT;
    const unsigned b0 = (high << (TBIT + 1)) | low;   // target bit = 0
    const unsigned b1 = b0 | (1u << TBIT);            // target bit = 1

    // Non-temporal streaming loads: each line is read exactly once.
    const f4 r0 = __builtin_nontemporal_load((const f4*)(sre + (size_t)b0 * BATCH));
    const f4 r1 = __builtin_nontemporal_load((const f4*)(sre + (size_t)b1 * BATCH));
    const f4 i0 = __builtin_nontemporal_load((const f4*)(sim + (size_t)b0 * BATCH));
    const f4 i1 = __builtin_nontemporal_load((const f4*)(sim + (size_t)b1 * BATCH));

    // 2x2 gate coefficients (row-major): m[r][c] — uniform, scalar-loaded.
    const float mr00 = mre[0], mr01 = mre[1], mr10 = mre[2], mr11 = mre[3];
    const float mi00 = mim[0], mi01 = mim[1], mi10 = mim[2], mi11 = mim[3];

    // ext_vector_type broadcasts scalars: elementwise over the 4-batch.
    const f4 or0 = mr00 * r0 + mr01 * r1 - (mi00 * i0 + mi01 * i1);
    const f4 oi0 = mr00 * i0 + mr01 * i1 + (mi00 * r0 + mi01 * r1);
    const f4 or1 = mr10 * r0 + mr11 * r1 - (mi10 * i0 + mi11 * i1);
    const f4 oi1 = mr10 * i0 + mr11 * i1 + (mi10 * r0 + mi11 * r1);

    float* ore = out;                                   // out[0] = real plane
    float* oim = out + (size_t)DIMQ * BATCH;            // out[1] = imag plane

    // Non-temporal streaming stores: full 64B lines covered per wave, no RFO,
    // no L2/LLC allocation of write-once lines.
    __builtin_nontemporal_store(or0, (f4*)(ore + (size_t)b0 * BATCH));
    __builtin_nontemporal_store(or1, (f4*)(ore + (size_t)b1 * BATCH));
    __builtin_nontemporal_store(oi0, (f4*)(oim + (size_t)b0 * BATCH));
    __builtin_nontemporal_store(oi1, (f4*)(oim + (size_t)b1 * BATCH));
}

extern "C" void kernel_launch(void* const* d_in, const int* in_sizes, int n_in,
                              void* d_out, int out_size, void* d_ws, size_t ws_size,
                              hipStream_t stream) {
    const float* sre = (const float*)d_in[0];
    const float* sim = (const float*)d_in[1];
    const float* mre = (const float*)d_in[2];
    const float* mim = (const float*)d_in[3];
    float* out = (float*)d_out;

    const int pairs = DIMQ / 2;           // 4,194,304
    dim3 block(256);
    dim3 grid(pairs / 256);               // 16384 blocks
    gate_q12_kernel<<<grid, block, 0, stream>>>(sre, sim, mre, mim, out);
}